// Round 3
// baseline (894.590 us; speedup 1.0000x reference)
//
#include <hip/hip_runtime.h>
#include <math.h>

#define KK 8
#define H 250          // SIZE == h1
#define MDIM 576
#define NB 2048
#define HA 100
#define ROWS (NB*KK)   // 16384
#define PQS 512        // PQ row stride: P at 0..249, Q at 256..505 (16B-aligned)
#define KP 1088        // padded K for out GEMM (1076 -> 34*32)
#define EPS 1e-5f

#define RCA 112        // pair rows per k_ca block (16 groups * 7)
#define GCA 16
#define NCA 384        // 250 ctx + 100 att + pad
#define SSTR 388       // epilogue slab stride (pad vs 384 for bank spread)

typedef unsigned short ushort_t;
typedef short short8 __attribute__((ext_vector_type(8)));
typedef float f32x4 __attribute__((ext_vector_type(4)));

__device__ __forceinline__ void wave_reduce2(float& a, float& b) {
#pragma unroll
    for (int m = 1; m < 64; m <<= 1) {
        a += __shfl_xor(a, m, 64);
        b += __shfl_xor(b, m, 64);
    }
}
__device__ __forceinline__ float wave_reduce1(float a) {
#pragma unroll
    for (int m = 1; m < 64; m <<= 1) a += __shfl_xor(a, m, 64);
    return a;
}

__device__ __forceinline__ void async_copy16(const void* g, void* l) {
    __builtin_amdgcn_global_load_lds(
        (const __attribute__((address_space(1))) void*)g,
        (__attribute__((address_space(3))) void*)l, 16, 0, 0);
}

__device__ __forceinline__ ushort_t f2bf(float v) {
    union { float f; unsigned int u; } c; c.f = v;
    unsigned int x = c.u;
    x += 0x7fff + ((x >> 16) & 1);   // RNE
    return (ushort_t)(x >> 16);
}

// s1 = LN(relu(state @ enc_W + enc_b)) -> Abuf cols [0,250) bf16
__global__ __launch_bounds__(256) void k_enc(const float* __restrict__ state,
    const float* __restrict__ W, const float* __restrict__ bias,
    const float* __restrict__ gam, const float* __restrict__ bet,
    ushort_t* __restrict__ Abuf)
{
    __shared__ __align__(16) float st[4][H][8];   // [wave][k][row]
    const int wave = threadIdx.x >> 6, lane = threadIdx.x & 63;
    const int row0 = (blockIdx.x * 4 + wave) * 8;

#pragma unroll
    for (int r = 0; r < 8; ++r)
        for (int kk = lane; kk < H; kk += 64)
            st[wave][kk][r] = state[(size_t)(row0 + r) * H + kk];
    __syncthreads();

    int c[4]; bool val[4]; const float* pW[4];
#pragma unroll
    for (int u = 0; u < 4; ++u) {
        c[u] = lane + 64 * u; val[u] = c[u] < H;
        pW[u] = W + (val[u] ? c[u] : 0);
    }
    float acc[8][4] = {};
    for (int kk = 0; kk < H; ++kk) {
        const float4 sA = *(const float4*)&st[wave][kk][0];
        const float4 sB = *(const float4*)&st[wave][kk][4];
        const float s[8] = {sA.x,sA.y,sA.z,sA.w,sB.x,sB.y,sB.z,sB.w};
        float w[4];
#pragma unroll
        for (int u = 0; u < 4; ++u) { w[u] = *pW[u]; pW[u] += H; }
#pragma unroll
        for (int u = 0; u < 4; ++u)
#pragma unroll
            for (int r = 0; r < 8; ++r)
                acc[r][u] = fmaf(s[r], w[u], acc[r][u]);
    }

    float bv[4], gv[4], btv[4];
#pragma unroll
    for (int u = 0; u < 4; ++u) {
        bv[u]  = val[u] ? bias[c[u]] : 0.f;
        gv[u]  = val[u] ? gam[c[u]]  : 0.f;
        btv[u] = val[u] ? bet[c[u]]  : 0.f;
    }
#pragma unroll
    for (int r = 0; r < 8; ++r) {
        float y[4]; float sm = 0.f, sq = 0.f;
#pragma unroll
        for (int u = 0; u < 4; ++u) {
            float z = val[u] ? fmaxf(acc[r][u] + bv[u], 0.f) : 0.f;
            y[u] = z; sm += z; sq += z * z;
        }
        wave_reduce2(sm, sq);
        const float mu = sm * (1.f / H);
        const float rs = rsqrtf(sq * (1.f / H) - mu * mu + EPS);
#pragma unroll
        for (int u = 0; u < 4; ++u) if (val[u]) {
            const float o = (y[u] - mu) * rs * gv[u] + btv[u];
            Abuf[(size_t)(row0 + r) * KP + c[u]] = f2bf(o);
        }
    }
}

// generic bf16 MFMA GEMM: C[m][n] = sum_k A[m][k]*B[n][k] (+bias[n])
// 64x64 tiles, BK=32, 4 waves 2x2, XOR-swizzled LDS (2-way = free, m136)
__global__ __launch_bounds__(256) void k_gemm(
    const ushort_t* __restrict__ A, int lda,
    const ushort_t* __restrict__ B, int ldb,
    float* __restrict__ C, int ldc,
    const float* __restrict__ bias,
    int ksteps, int ntiles, int nlim)
{
    __shared__ __align__(16) ushort_t As[64 * 32];
    __shared__ __align__(16) ushort_t Bs[64 * 32];
    const int tid  = threadIdx.x;
    const int lane = tid & 63, wave = tid >> 6;
    const int wm = wave >> 1, wn = wave & 1;
    const int m0 = ((int)blockIdx.x / ntiles) * 64;
    const int n0 = ((int)blockIdx.x % ntiles) * 64;

    const int srow = tid >> 2;
    const int cs   = tid & 3;
    const int cl   = cs ^ ((srow >> 1) & 3);
    const ushort_t* gA = A + (size_t)(m0 + srow) * lda + cl * 8;
    const ushort_t* gB = B + (size_t)(n0 + srow) * ldb + cl * 8;
    ushort_t* lA = &As[tid * 8];
    ushort_t* lB = &Bs[tid * 8];

    const int q  = lane >> 4;
    const int fr = lane & 15;
    int aoff[2], boff[2];
#pragma unroll
    for (int s = 0; s < 2; ++s) {
        const int ra = wm * 32 + s * 16 + fr;
        aoff[s] = (ra * 4 + (q ^ ((ra >> 1) & 3))) * 8;
        const int rb = wn * 32 + s * 16 + fr;
        boff[s] = (rb * 4 + (q ^ ((rb >> 1) & 3))) * 8;
    }

    f32x4 acc[2][2] = {};
    for (int ks = 0; ks < ksteps; ++ks) {
        const int k0 = ks * 32;
        async_copy16(gA + k0, lA);
        async_copy16(gB + k0, lB);
        __syncthreads();
        short8 a[2], b[2];
#pragma unroll
        for (int s = 0; s < 2; ++s) {
            a[s] = *(const short8*)&As[aoff[s]];
            b[s] = *(const short8*)&Bs[boff[s]];
        }
#pragma unroll
        for (int ms = 0; ms < 2; ++ms)
#pragma unroll
            for (int ns = 0; ns < 2; ++ns)
                acc[ms][ns] = __builtin_amdgcn_mfma_f32_16x16x32_bf16(
                    a[ms], b[ns], acc[ms][ns], 0, 0, 0);
        __syncthreads();
    }

#pragma unroll
    for (int ms = 0; ms < 2; ++ms)
#pragma unroll
        for (int ns = 0; ns < 2; ++ns) {
            const int n_abs = n0 + wn * 32 + ns * 16 + fr;
            if (n_abs >= nlim) continue;
            const float bv = bias ? bias[n_abs] : 0.f;
#pragma unroll
            for (int reg = 0; reg < 4; ++reg) {
                const int m_abs = m0 + wm * 32 + ms * 16 + q * 4 + reg;
                C[(size_t)m_abs * ldc + n_abs] = acc[ms][ns][reg] + bv;
            }
        }
}

// fused core-LN -> [ctxW|attW1] MFMA GEMM -> LNs -> sigmoid -> partner-sum
// One block per 16 groups (112 pair rows). 512 threads = 8 waves (2x4 tile grid).
__global__ __launch_bounds__(512) void k_ca(
    const float* __restrict__ PQ,
    const float* __restrict__ core_b, const float* __restrict__ core_g, const float* __restrict__ core_bt,
    const ushort_t* __restrict__ Wca,   // [384][256] bf16
    const float* __restrict__ ctx_b, const float* __restrict__ ctx_g, const float* __restrict__ ctx_bt,
    const float* __restrict__ att_b1, const float* __restrict__ att_g, const float* __restrict__ att_bt,
    const float* __restrict__ attW2, const float* __restrict__ att_b2,
    ushort_t* __restrict__ Abuf)
{
    __shared__ __align__(16) ushort_t As[RCA * 32];   // 7168 B  (one 32-col k-slice)
    __shared__ __align__(16) ushort_t Bs[NCA * 32];   // 24576 B
    __shared__ float Sred[8 * SSTR];                  // 12416 B (8-row epilogue slab)
    __shared__ float effs[GCA * 256];                 // 16384 B
    __shared__ float stats[RCA * 2];                  // 896 B   (mu, rs per row)

    const int tid = threadIdx.x, lane = tid & 63, wave = tid >> 6;
    const int g0 = (int)blockIdx.x * GCA;

    for (int idx = tid; idx < GCA * 256; idx += 512) effs[idx] = 0.f;

    // ---- phase 1: LN stats of relu(P+Q+core_b) per row (no materialization) ----
    {
        const int c = 4 * lane;
        float cb[4];
#pragma unroll
        for (int t = 0; t < 4; ++t) cb[t] = (c + t < H) ? core_b[c + t] : 0.f;
#pragma unroll 2
        for (int rr = 0; rr < 14; ++rr) {
            const int r  = wave * 14 + rr;
            const int gl = r / 7, jj = r - gl * 7;
            const int g  = g0 + gl, i = g & 7;
            const int j  = jj + (jj >= i ? 1 : 0);
            const int qr = (g & ~7) + j;
            const float4 pv = *(const float4*)&PQ[(size_t)g  * PQS + c];
            const float4 qv = *(const float4*)&PQ[(size_t)qr * PQS + 256 + c];
            const float pe[4] = {pv.x, pv.y, pv.z, pv.w};
            const float qe[4] = {qv.x, qv.y, qv.z, qv.w};
            float sm = 0.f, sq = 0.f;
#pragma unroll
            for (int t = 0; t < 4; ++t) {
                const float z = (c + t < H) ? fmaxf(pe[t] + qe[t] + cb[t], 0.f) : 0.f;
                sm += z; sq += z * z;
            }
            wave_reduce2(sm, sq);
            if (lane == 0) {
                const float mu = sm * (1.f / H);
                stats[r * 2]     = mu;
                stats[r * 2 + 1] = rsqrtf(sq * (1.f / H) - mu * mu + EPS);
            }
        }
    }
    __syncthreads();

    // ---- phase 2: GEMM. A-slice recomputed per k-step; B async-staged ----
    const int wm = wave >> 2, wn = wave & 3;          // 2 x 4 wave grid
    const int q = lane >> 4, fr = lane & 15;
    const int nmt = wm ? 3 : 4;                        // wm0: mt 0..3, wm1: mt 4..6

    // A-staging mapping: thread -> (row, chunk)
    const int ar  = tid >> 2;
    const int acb = tid & 3;
    const bool s_on = (ar < RCA);
    int s_g = 0, s_qr = 0; float s_mu = 0.f, s_rs = 0.f;
    if (s_on) {
        const int gl = ar / 7, jj = ar - gl * 7;
        s_g = g0 + gl;
        const int i = s_g & 7;
        const int j = jj + (jj >= i ? 1 : 0);
        s_qr = (s_g & ~7) + j;
        s_mu = stats[ar * 2]; s_rs = stats[ar * 2 + 1];
    }

    f32x4 acc[4][6] = {};
    for (int ks = 0; ks < 8; ++ks) {
        const int k0 = ks * 32;
        // A: recompute core_out bf16 slice (VALU ds_write, swizzled)
        if (s_on) {
            const int kc = k0 + acb * 8;
            const float4 p0 = *(const float4*)&PQ[(size_t)s_g  * PQS + kc];
            const float4 p1 = *(const float4*)&PQ[(size_t)s_g  * PQS + kc + 4];
            const float4 q0 = *(const float4*)&PQ[(size_t)s_qr * PQS + 256 + kc];
            const float4 q1 = *(const float4*)&PQ[(size_t)s_qr * PQS + 256 + kc + 4];
            const float pe[8] = {p0.x,p0.y,p0.z,p0.w,p1.x,p1.y,p1.z,p1.w};
            const float qe[8] = {q0.x,q0.y,q0.z,q0.w,q1.x,q1.y,q1.z,q1.w};
            short8 ob;
#pragma unroll
            for (int e = 0; e < 8; ++e) {
                const int kk = kc + e;
                float v = 0.f;
                if (kk < H) {
                    const float z = fmaxf(pe[e] + qe[e] + core_b[kk], 0.f);
                    v = (z - s_mu) * s_rs * core_g[kk] + core_bt[kk];
                }
                ob[e] = (short)f2bf(v);
            }
            const int pos = acb ^ ((ar >> 1) & 3);
            *(short8*)&As[(ar * 4 + pos) * 8] = ob;
        }
        // B: async global->LDS, 3 chunks/thread, global-side swizzle
#pragma unroll
        for (int it = 0; it < 3; ++it) {
            const int ci  = it * 512 + tid;
            const int rb  = ci >> 2, cb2 = ci & 3;
            const int clb = cb2 ^ ((rb >> 1) & 3);
            async_copy16(Wca + (size_t)rb * 256 + k0 + clb * 8, &Bs[ci * 8]);
        }
        __syncthreads();
        short8 a[4];
#pragma unroll
        for (int mtl = 0; mtl < 4; ++mtl) {
            if (mtl < nmt) {
                const int row = wm * 64 + mtl * 16 + fr;
                a[mtl] = *(const short8*)&As[(row * 4 + (q ^ ((row >> 1) & 3))) * 8];
            }
        }
#pragma unroll
        for (int ntl = 0; ntl < 6; ++ntl) {
            const int n = wn * 96 + ntl * 16 + fr;
            const short8 b = *(const short8*)&Bs[(n * 4 + (q ^ ((n >> 1) & 3))) * 8];
#pragma unroll
            for (int mtl = 0; mtl < 4; ++mtl)
                if (mtl < nmt)
                    acc[mtl][ntl] = __builtin_amdgcn_mfma_f32_16x16x32_bf16(
                        a[mtl], b, acc[mtl][ntl], 0, 0, 0);
        }
        __syncthreads();
    }

    // ---- phase 3: epilogue, 8-row slabs through LDS ----
    const float ab2 = att_b2[0];
#pragma unroll 1
    for (int mt = 0; mt < 7; ++mt) {
        const int  mwm = (mt >= 4) ? 1 : 0;
        const int  mtl = mt - 4 * mwm;
        const bool own = (wm == mwm);
#pragma unroll 1
        for (int h = 0; h < 2; ++h) {
            __syncthreads();
            if (own && (q >> 1) == h) {
                const int rr = (q & 1) * 4;
#pragma unroll
                for (int ntl = 0; ntl < 6; ++ntl) {
                    const int col = wn * 96 + ntl * 16 + fr;
#pragma unroll
                    for (int reg = 0; reg < 4; ++reg)
                        Sred[(rr + reg) * SSTR + col] = acc[mtl][ntl][reg];
                }
            }
            __syncthreads();
            // LN + att + gate: wave handles local row = wave
            const int r  = mt * 16 + h * 8 + wave;   // < 112 always
            const int gl = r / 7;
            float sv[6];
            float smc = 0.f, sqc = 0.f, sma = 0.f, sqa = 0.f;
#pragma unroll
            for (int u = 0; u < 6; ++u) {
                const int cc = lane + 64 * u;
                const float v = Sred[wave * SSTR + cc];
                if (cc < H) {
                    const float z = fmaxf(v + ctx_b[cc], 0.f);
                    sv[u] = z; smc += z; sqc += z * z;
                } else if (cc < H + HA) {
                    const float za = tanhf(v + att_b1[cc - H]);
                    sv[u] = za; sma += za; sqa += za * za;
                } else sv[u] = 0.f;
            }
            wave_reduce2(smc, sqc);
            wave_reduce2(sma, sqa);
            const float muC = smc * (1.f / H);
            const float rsC = rsqrtf(sqc * (1.f / H) - muC * muC + EPS);
            const float muA = sma * (1.f / HA);
            const float rsA = rsqrtf(sqa * (1.f / HA) - muA * muA + EPS);
            float dot = 0.f;
#pragma unroll
            for (int u = 0; u < 6; ++u) {
                const int cc = lane + 64 * u;
                if (cc >= H && cc < H + HA) {
                    const float ath = (sv[u] - muA) * rsA * att_g[cc - H] + att_bt[cc - H];
                    dot += ath * attW2[cc - H];
                }
            }
            dot = wave_reduce1(dot);
            const float ag = 1.f / (1.f + expf(-(dot + ab2)));
#pragma unroll
            for (int u = 0; u < 4; ++u) {
                const int cc = lane + 64 * u;
                if (cc < H) {
                    const float ctxo = (sv[u] - muC) * rsC * ctx_g[cc] + ctx_bt[cc];
                    atomicAdd(&effs[gl * 256 + cc], ag * ctxo);
                }
            }
        }
    }
    __syncthreads();
    for (int idx = tid; idx < GCA * 256; idx += 512) {
        const int gl = idx >> 8, cc = idx & 255;
        if (cc < H)
            Abuf[(size_t)(g0 + gl) * KP + H + cc] = f2bf(effs[idx]);
    }
}

// Abuf cols [500,1088): x (bf16) + zero pad
__global__ __launch_bounds__(256) void k_prepx(const float* __restrict__ x,
                                               ushort_t* __restrict__ Abuf)
{
    const int row = blockIdx.x;
    for (int c = 500 + threadIdx.x; c < KP; c += 256) {
        const float v = (c < 500 + MDIM) ? x[(size_t)row * MDIM + (c - 500)] : 0.f;
        Abuf[(size_t)row * KP + c] = f2bf(v);
    }
}

// Wt[n][k] = out_W[k][n], 256 x 1088 bf16
__global__ __launch_bounds__(256) void k_prepw(const float* __restrict__ Wo,
                                               ushort_t* __restrict__ Wt)
{
    const int n = blockIdx.x;
    for (int k = threadIdx.x; k < KP; k += 256) {
        const float v = (n < H && k < 1076) ? Wo[(size_t)k * H + n] : 0.f;
        Wt[(size_t)n * KP + k] = f2bf(v);
    }
}

// Wpq[n][k]: n<250 -> core_W[k][n] (P); 256<=n<506 -> core_W[250+k][n-256] (Q)
__global__ __launch_bounds__(256) void k_prep_wpq(const float* __restrict__ coreW,
                                                  ushort_t* __restrict__ Wpq)
{
    const int n = blockIdx.x;   // 0..511
    const int k = threadIdx.x;  // 0..255
    float v = 0.f;
    if (k < H) {
        if (n < H)                    v = coreW[(size_t)k * H + n];
        else if (n >= 256 && n < 506) v = coreW[(size_t)(H + k) * H + (n - 256)];
    }
    Wpq[(size_t)n * 256 + k] = f2bf(v);
}

// Wca[n][k]: n<250 -> ctxW[k][n]; 250<=n<350 -> attW1[k][n-250]
__global__ __launch_bounds__(256) void k_prep_wca(const float* __restrict__ ctxW,
                                                  const float* __restrict__ attW1,
                                                  ushort_t* __restrict__ Wca)
{
    const int n = blockIdx.x;   // 0..383
    const int k = threadIdx.x;  // 0..255
    float v = 0.f;
    if (k < H) {
        if (n < H)           v = ctxW[(size_t)k * H + n];
        else if (n < H + HA) v = attW1[(size_t)k * HA + (n - H)];
    }
    Wca[(size_t)n * 256 + k] = f2bf(v);
}

extern "C" void kernel_launch(void* const* d_in, const int* in_sizes, int n_in,
                              void* d_out, int out_size, void* d_ws, size_t ws_size,
                              hipStream_t stream)
{
    const float* x      = (const float*)d_in[0];
    const float* state  = (const float*)d_in[1];
    const float* enc_W  = (const float*)d_in[2];
    const float* enc_b  = (const float*)d_in[3];
    const float* enc_g  = (const float*)d_in[4];
    const float* enc_bt = (const float*)d_in[5];
    const float* core_W = (const float*)d_in[6];
    const float* core_b = (const float*)d_in[7];
    const float* core_g = (const float*)d_in[8];
    const float* core_bt= (const float*)d_in[9];
    const float* ctx_W  = (const float*)d_in[10];
    const float* ctx_b  = (const float*)d_in[11];
    const float* ctx_g  = (const float*)d_in[12];
    const float* ctx_bt = (const float*)d_in[13];
    const float* att_W1 = (const float*)d_in[14];
    const float* att_b1 = (const float*)d_in[15];
    const float* att_g  = (const float*)d_in[16];
    const float* att_bt = (const float*)d_in[17];
    const float* att_W2 = (const float*)d_in[18];
    const float* att_b2 = (const float*)d_in[19];
    const float* out_W  = (const float*)d_in[20];
    const float* out_b  = (const float*)d_in[21];
    float* out = (float*)d_out;

    float* PQ       = (float*)d_ws;                        // 16384*512 f32
    ushort_t* Abuf  = (ushort_t*)(PQ + (size_t)ROWS * PQS);// 16384*1088 bf16
    ushort_t* Wt    = Abuf + (size_t)ROWS * KP;            // 256*1088
    ushort_t* Wpq   = Wt + (size_t)256 * KP;               // 512*256
    ushort_t* Wca   = Wpq + (size_t)512 * 256;             // 384*256

    k_prepw  <<<256, 256, 0, stream>>>(out_W, Wt);
    k_prep_wpq<<<512, 256, 0, stream>>>(core_W, Wpq);
    k_prep_wca<<<384, 256, 0, stream>>>(ctx_W, att_W1, Wca);
    k_prepx  <<<ROWS, 256, 0, stream>>>(x, Abuf);
    k_enc    <<<ROWS / 32, 256, 0, stream>>>(state, enc_W, enc_b, enc_g, enc_bt, Abuf);
    // PQ = s1 @ [W_top | W_bot]  (bf16 MFMA)
    k_gemm   <<<(ROWS / 64) * 8, 256, 0, stream>>>(Abuf, KP, Wpq, 256, PQ, PQS,
                                                   nullptr, 8, 8, 512);
    k_ca     <<<ROWS / GCA, 512, 0, stream>>>(PQ, core_b, core_g, core_bt, Wca,
                                              ctx_b, ctx_g, ctx_bt,
                                              att_b1, att_g, att_bt, att_W2, att_b2,
                                              Abuf);
    // out = [s1 | eff | x] @ out_W + b  (bf16 MFMA)
    k_gemm   <<<(ROWS / 64) * 4, 256, 0, stream>>>(Abuf, KP, Wt, KP, out, H,
                                                   out_b, KP / 32, 4, H);
}

// Round 4
// 607.782 us; speedup vs baseline: 1.4719x; 1.4719x over previous
//
#include <hip/hip_runtime.h>
#include <math.h>

#define KK 8
#define H 250          // SIZE == h1
#define MDIM 576
#define NB 2048
#define HA 100
#define ROWS (NB*KK)   // 16384
#define PQS 512        // PQ row stride: P at 0..249, Q at 256..505 (16B-aligned)
#define KP 1088        // padded K for out GEMM (1076 -> 34*32)
#define EPS 1e-5f

#define RCA 112        // pair rows per k_ca block (16 groups * 7)
#define GCA 16
#define NCA 384        // 250 ctx + 100 att + pad
#define SSTR 388       // epilogue slab stride (pad vs 384 for bank spread)

typedef unsigned short ushort_t;
typedef short short8 __attribute__((ext_vector_type(8)));
typedef float f32x4 __attribute__((ext_vector_type(4)));

__device__ __forceinline__ void wave_reduce2(float& a, float& b) {
#pragma unroll
    for (int m = 1; m < 64; m <<= 1) {
        a += __shfl_xor(a, m, 64);
        b += __shfl_xor(b, m, 64);
    }
}
__device__ __forceinline__ float wave_reduce1(float a) {
#pragma unroll
    for (int m = 1; m < 64; m <<= 1) a += __shfl_xor(a, m, 64);
    return a;
}

__device__ __forceinline__ void async_copy16(const void* g, void* l) {
    __builtin_amdgcn_global_load_lds(
        (const __attribute__((address_space(1))) void*)g,
        (__attribute__((address_space(3))) void*)l, 16, 0, 0);
}

__device__ __forceinline__ ushort_t f2bf(float v) {
    union { float f; unsigned int u; } c; c.f = v;
    unsigned int x = c.u;
    x += 0x7fff + ((x >> 16) & 1);   // RNE
    return (ushort_t)(x >> 16);
}

// s1 = LN(relu(state @ enc_W + enc_b)) -> Abuf cols [0,250) bf16
__global__ __launch_bounds__(256) void k_enc(const float* __restrict__ state,
    const float* __restrict__ W, const float* __restrict__ bias,
    const float* __restrict__ gam, const float* __restrict__ bet,
    ushort_t* __restrict__ Abuf)
{
    __shared__ __align__(16) float st[4][H][8];   // [wave][k][row]
    const int wave = threadIdx.x >> 6, lane = threadIdx.x & 63;
    const int row0 = (blockIdx.x * 4 + wave) * 8;

#pragma unroll
    for (int r = 0; r < 8; ++r)
        for (int kk = lane; kk < H; kk += 64)
            st[wave][kk][r] = state[(size_t)(row0 + r) * H + kk];
    __syncthreads();

    int c[4]; bool val[4]; const float* pW[4];
#pragma unroll
    for (int u = 0; u < 4; ++u) {
        c[u] = lane + 64 * u; val[u] = c[u] < H;
        pW[u] = W + (val[u] ? c[u] : 0);
    }
    float acc[8][4] = {};
    for (int kk = 0; kk < H; ++kk) {
        const float4 sA = *(const float4*)&st[wave][kk][0];
        const float4 sB = *(const float4*)&st[wave][kk][4];
        const float s[8] = {sA.x,sA.y,sA.z,sA.w,sB.x,sB.y,sB.z,sB.w};
        float w[4];
#pragma unroll
        for (int u = 0; u < 4; ++u) { w[u] = *pW[u]; pW[u] += H; }
#pragma unroll
        for (int u = 0; u < 4; ++u)
#pragma unroll
            for (int r = 0; r < 8; ++r)
                acc[r][u] = fmaf(s[r], w[u], acc[r][u]);
    }

    float bv[4], gv[4], btv[4];
#pragma unroll
    for (int u = 0; u < 4; ++u) {
        bv[u]  = val[u] ? bias[c[u]] : 0.f;
        gv[u]  = val[u] ? gam[c[u]]  : 0.f;
        btv[u] = val[u] ? bet[c[u]]  : 0.f;
    }
#pragma unroll
    for (int r = 0; r < 8; ++r) {
        float y[4]; float sm = 0.f, sq = 0.f;
#pragma unroll
        for (int u = 0; u < 4; ++u) {
            float z = val[u] ? fmaxf(acc[r][u] + bv[u], 0.f) : 0.f;
            y[u] = z; sm += z; sq += z * z;
        }
        wave_reduce2(sm, sq);
        const float mu = sm * (1.f / H);
        const float rs = rsqrtf(sq * (1.f / H) - mu * mu + EPS);
#pragma unroll
        for (int u = 0; u < 4; ++u) if (val[u]) {
            const float o = (y[u] - mu) * rs * gv[u] + btv[u];
            Abuf[(size_t)(row0 + r) * KP + c[u]] = f2bf(o);
        }
    }
}

// generic bf16 MFMA GEMM: C[m][n] = sum_k A[m][k]*B[n][k] (+bias[n])
__global__ __launch_bounds__(256) void k_gemm(
    const ushort_t* __restrict__ A, int lda,
    const ushort_t* __restrict__ B, int ldb,
    float* __restrict__ C, int ldc,
    const float* __restrict__ bias,
    int ksteps, int ntiles, int nlim)
{
    __shared__ __align__(16) ushort_t As[64 * 32];
    __shared__ __align__(16) ushort_t Bs[64 * 32];
    const int tid  = threadIdx.x;
    const int lane = tid & 63, wave = tid >> 6;
    const int wm = wave >> 1, wn = wave & 1;
    const int m0 = ((int)blockIdx.x / ntiles) * 64;
    const int n0 = ((int)blockIdx.x % ntiles) * 64;

    const int srow = tid >> 2;
    const int cs   = tid & 3;
    const int cl   = cs ^ ((srow >> 1) & 3);
    const ushort_t* gA = A + (size_t)(m0 + srow) * lda + cl * 8;
    const ushort_t* gB = B + (size_t)(n0 + srow) * ldb + cl * 8;
    ushort_t* lA = &As[tid * 8];
    ushort_t* lB = &Bs[tid * 8];

    const int q  = lane >> 4;
    const int fr = lane & 15;
    int aoff[2], boff[2];
#pragma unroll
    for (int s = 0; s < 2; ++s) {
        const int ra = wm * 32 + s * 16 + fr;
        aoff[s] = (ra * 4 + (q ^ ((ra >> 1) & 3))) * 8;
        const int rb = wn * 32 + s * 16 + fr;
        boff[s] = (rb * 4 + (q ^ ((rb >> 1) & 3))) * 8;
    }

    f32x4 acc[2][2] = {};
    for (int ks = 0; ks < ksteps; ++ks) {
        const int k0 = ks * 32;
        async_copy16(gA + k0, lA);
        async_copy16(gB + k0, lB);
        __syncthreads();
        short8 a[2], b[2];
#pragma unroll
        for (int s = 0; s < 2; ++s) {
            a[s] = *(const short8*)&As[aoff[s]];
            b[s] = *(const short8*)&Bs[boff[s]];
        }
#pragma unroll
        for (int ms = 0; ms < 2; ++ms)
#pragma unroll
            for (int ns = 0; ns < 2; ++ns)
                acc[ms][ns] = __builtin_amdgcn_mfma_f32_16x16x32_bf16(
                    a[ms], b[ns], acc[ms][ns], 0, 0, 0);
        __syncthreads();
    }

#pragma unroll
    for (int ms = 0; ms < 2; ++ms)
#pragma unroll
        for (int ns = 0; ns < 2; ++ns) {
            const int n_abs = n0 + wn * 32 + ns * 16 + fr;
            if (n_abs >= nlim) continue;
            const float bv = bias ? bias[n_abs] : 0.f;
#pragma unroll
            for (int reg = 0; reg < 4; ++reg) {
                const int m_abs = m0 + wm * 32 + ms * 16 + q * 4 + reg;
                C[(size_t)m_abs * ldc + n_abs] = acc[ms][ns][reg] + bv;
            }
        }
}

// fused core-LN -> [ctxW|attW1] MFMA GEMM -> LNs -> sigmoid -> partner-sum
// One block per 16 groups (112 pair rows). 512 threads = 8 waves (2x4 tile grid).
// NOTE: every acc[][] index is compile-time (fully unrolled epilogue) — round-3's
// dynamic indexing spilled the accumulators to scratch (1.6 GB of HBM writes).
__global__ __launch_bounds__(512) void k_ca(
    const float* __restrict__ PQ,
    const float* __restrict__ core_b, const float* __restrict__ core_g, const float* __restrict__ core_bt,
    const ushort_t* __restrict__ Wca,   // [384][256] bf16
    const float* __restrict__ ctx_b, const float* __restrict__ ctx_g, const float* __restrict__ ctx_bt,
    const float* __restrict__ att_b1, const float* __restrict__ att_g, const float* __restrict__ att_bt,
    const float* __restrict__ attW2, const float* __restrict__ att_b2,
    ushort_t* __restrict__ Abuf)
{
    __shared__ __align__(16) ushort_t As[RCA * 32];   // 7168 B  (one 32-col k-slice)
    __shared__ __align__(16) ushort_t Bs[NCA * 32];   // 24576 B
    __shared__ float Sred[16 * SSTR];                 // 24832 B (16-row tile slab)
    __shared__ float effs[GCA * 256];                 // 16384 B
    __shared__ float stats[RCA * 2];                  // 896 B   (mu, rs per row)

    const int tid = threadIdx.x, lane = tid & 63, wave = tid >> 6;
    const int g0 = (int)blockIdx.x * GCA;

    for (int idx = tid; idx < GCA * 256; idx += 512) effs[idx] = 0.f;

    // ---- phase 1: LN stats of relu(P+Q+core_b) per row ----
    {
        const int c = 4 * lane;
        float cb[4];
#pragma unroll
        for (int t = 0; t < 4; ++t) cb[t] = (c + t < H) ? core_b[c + t] : 0.f;
#pragma unroll 2
        for (int rr = 0; rr < 14; ++rr) {
            const int r  = wave * 14 + rr;
            const int gl = r / 7, jj = r - gl * 7;
            const int g  = g0 + gl, i = g & 7;
            const int j  = jj + (jj >= i ? 1 : 0);
            const int qr = (g & ~7) + j;
            const float4 pv = *(const float4*)&PQ[(size_t)g  * PQS + c];
            const float4 qv = *(const float4*)&PQ[(size_t)qr * PQS + 256 + c];
            const float pe[4] = {pv.x, pv.y, pv.z, pv.w};
            const float qe[4] = {qv.x, qv.y, qv.z, qv.w};
            float sm = 0.f, sq = 0.f;
#pragma unroll
            for (int t = 0; t < 4; ++t) {
                const float z = (c + t < H) ? fmaxf(pe[t] + qe[t] + cb[t], 0.f) : 0.f;
                sm += z; sq += z * z;
            }
            wave_reduce2(sm, sq);
            if (lane == 0) {
                const float mu = sm * (1.f / H);
                stats[r * 2]     = mu;
                stats[r * 2 + 1] = rsqrtf(sq * (1.f / H) - mu * mu + EPS);
            }
        }
    }
    __syncthreads();

    // ---- phase 2: GEMM. A-slice recomputed per k-step; B async-staged ----
    const int wm = wave >> 2, wn = wave & 3;          // 2 x 4 wave grid
    const int q = lane >> 4, fr = lane & 15;
    const int nmt = wm ? 3 : 4;                        // wm0: mt 0..3, wm1: mt 4..6

    const int ar  = tid >> 2;
    const int acb = tid & 3;
    const bool s_on = (ar < RCA);
    int s_g = 0, s_qr = 0; float s_mu = 0.f, s_rs = 0.f;
    if (s_on) {
        const int gl = ar / 7, jj = ar - gl * 7;
        s_g = g0 + gl;
        const int i = s_g & 7;
        const int j = jj + (jj >= i ? 1 : 0);
        s_qr = (s_g & ~7) + j;
        s_mu = stats[ar * 2]; s_rs = stats[ar * 2 + 1];
    }

    f32x4 acc[4][6] = {};
    for (int ks = 0; ks < 8; ++ks) {
        const int k0 = ks * 32;
        if (s_on) {
            const int kc = k0 + acb * 8;
            const float4 p0 = *(const float4*)&PQ[(size_t)s_g  * PQS + kc];
            const float4 p1 = *(const float4*)&PQ[(size_t)s_g  * PQS + kc + 4];
            const float4 q0 = *(const float4*)&PQ[(size_t)s_qr * PQS + 256 + kc];
            const float4 q1 = *(const float4*)&PQ[(size_t)s_qr * PQS + 256 + kc + 4];
            const float pe[8] = {p0.x,p0.y,p0.z,p0.w,p1.x,p1.y,p1.z,p1.w};
            const float qe[8] = {q0.x,q0.y,q0.z,q0.w,q1.x,q1.y,q1.z,q1.w};
            short8 ob;
#pragma unroll
            for (int e = 0; e < 8; ++e) {
                const int kk = kc + e;
                float v = 0.f;
                if (kk < H) {
                    const float z = fmaxf(pe[e] + qe[e] + core_b[kk], 0.f);
                    v = (z - s_mu) * s_rs * core_g[kk] + core_bt[kk];
                }
                ob[e] = (short)f2bf(v);
            }
            const int pos = acb ^ ((ar >> 1) & 3);
            *(short8*)&As[(ar * 4 + pos) * 8] = ob;
        }
#pragma unroll
        for (int it = 0; it < 3; ++it) {
            const int ci  = it * 512 + tid;
            const int rb  = ci >> 2, cb2 = ci & 3;
            const int clb = cb2 ^ ((rb >> 1) & 3);
            async_copy16(Wca + (size_t)rb * 256 + k0 + clb * 8, &Bs[ci * 8]);
        }
        __syncthreads();
        short8 a[4];
#pragma unroll
        for (int mtl = 0; mtl < 4; ++mtl) {
            if (mtl < nmt) {
                const int row = wm * 64 + mtl * 16 + fr;
                a[mtl] = *(const short8*)&As[(row * 4 + (q ^ ((row >> 1) & 3))) * 8];
            }
        }
#pragma unroll
        for (int ntl = 0; ntl < 6; ++ntl) {
            const int n = wn * 96 + ntl * 16 + fr;
            const short8 b = *(const short8*)&Bs[(n * 4 + (q ^ ((n >> 1) & 3))) * 8];
#pragma unroll
            for (int mtl = 0; mtl < 4; ++mtl)
                if (mtl < nmt)
                    acc[mtl][ntl] = __builtin_amdgcn_mfma_f32_16x16x32_bf16(
                        a[mtl], b, acc[mtl][ntl], 0, 0, 0);
        }
        __syncthreads();
    }

    // ---- phase 3: epilogue, one 16-row tile at a time (FULLY unrolled) ----
    const float ab2 = att_b2[0];
#pragma unroll
    for (int mt = 0; mt < 7; ++mt) {
        const int mwm = (mt >= 4) ? 1 : 0;   // compile-time
        const int mtl = mt - 4 * mwm;        // compile-time
        __syncthreads();
        if (wm == mwm) {
#pragma unroll
            for (int ntl = 0; ntl < 6; ++ntl) {
                const int col = wn * 96 + ntl * 16 + fr;
#pragma unroll
                for (int reg = 0; reg < 4; ++reg)
                    Sred[(q * 4 + reg) * SSTR + col] = acc[mtl][ntl][reg];
            }
        }
        __syncthreads();
#pragma unroll
        for (int rh = 0; rh < 2; ++rh) {
            const int rloc = wave + rh * 8;          // 0..15
            const int r    = mt * 16 + rloc;         // 0..111
            const int gl   = r / 7;
            float sv[6];
            float smc = 0.f, sqc = 0.f, sma = 0.f, sqa = 0.f;
#pragma unroll
            for (int u = 0; u < 6; ++u) {
                const int cc = lane + 64 * u;
                const float v = Sred[rloc * SSTR + cc];
                if (cc < H) {
                    const float z = fmaxf(v + ctx_b[cc], 0.f);
                    sv[u] = z; smc += z; sqc += z * z;
                } else if (cc < H + HA) {
                    const float za = tanhf(v + att_b1[cc - H]);
                    sv[u] = za; sma += za; sqa += za * za;
                } else sv[u] = 0.f;
            }
            wave_reduce2(smc, sqc);
            wave_reduce2(sma, sqa);
            const float muC = smc * (1.f / H);
            const float rsC = rsqrtf(sqc * (1.f / H) - muC * muC + EPS);
            const float muA = sma * (1.f / HA);
            const float rsA = rsqrtf(sqa * (1.f / HA) - muA * muA + EPS);
            float dot = 0.f;
#pragma unroll
            for (int u = 0; u < 6; ++u) {
                const int cc = lane + 64 * u;
                if (cc >= H && cc < H + HA) {
                    const float ath = (sv[u] - muA) * rsA * att_g[cc - H] + att_bt[cc - H];
                    dot += ath * attW2[cc - H];
                }
            }
            dot = wave_reduce1(dot);
            const float ag = 1.f / (1.f + expf(-(dot + ab2)));
#pragma unroll
            for (int u = 0; u < 4; ++u) {
                const int cc = lane + 64 * u;
                if (cc < H) {
                    const float ctxo = (sv[u] - muC) * rsC * ctx_g[cc] + ctx_bt[cc];
                    atomicAdd(&effs[gl * 256 + cc], ag * ctxo);
                }
            }
        }
    }
    __syncthreads();
    for (int idx = tid; idx < GCA * 256; idx += 512) {
        const int gl = idx >> 8, cc = idx & 255;
        if (cc < H)
            Abuf[(size_t)(g0 + gl) * KP + H + cc] = f2bf(effs[idx]);
    }
}

// Abuf cols [500,1088): x (bf16) + zero pad
__global__ __launch_bounds__(256) void k_prepx(const float* __restrict__ x,
                                               ushort_t* __restrict__ Abuf)
{
    const int row = blockIdx.x;
    for (int c = 500 + threadIdx.x; c < KP; c += 256) {
        const float v = (c < 500 + MDIM) ? x[(size_t)row * MDIM + (c - 500)] : 0.f;
        Abuf[(size_t)row * KP + c] = f2bf(v);
    }
}

// Wt[n][k] = out_W[k][n], 256 x 1088 bf16
__global__ __launch_bounds__(256) void k_prepw(const float* __restrict__ Wo,
                                               ushort_t* __restrict__ Wt)
{
    const int n = blockIdx.x;
    for (int k = threadIdx.x; k < KP; k += 256) {
        const float v = (n < H && k < 1076) ? Wo[(size_t)k * H + n] : 0.f;
        Wt[(size_t)n * KP + k] = f2bf(v);
    }
}

// Wpq[n][k]: n<250 -> core_W[k][n] (P); 256<=n<506 -> core_W[250+k][n-256] (Q)
__global__ __launch_bounds__(256) void k_prep_wpq(const float* __restrict__ coreW,
                                                  ushort_t* __restrict__ Wpq)
{
    const int n = blockIdx.x;   // 0..511
    const int k = threadIdx.x;  // 0..255
    float v = 0.f;
    if (k < H) {
        if (n < H)                    v = coreW[(size_t)k * H + n];
        else if (n >= 256 && n < 506) v = coreW[(size_t)(H + k) * H + (n - 256)];
    }
    Wpq[(size_t)n * 256 + k] = f2bf(v);
}

// Wca[n][k]: n<250 -> ctxW[k][n]; 250<=n<350 -> attW1[k][n-250]
__global__ __launch_bounds__(256) void k_prep_wca(const float* __restrict__ ctxW,
                                                  const float* __restrict__ attW1,
                                                  ushort_t* __restrict__ Wca)
{
    const int n = blockIdx.x;   // 0..383
    const int k = threadIdx.x;  // 0..255
    float v = 0.f;
    if (k < H) {
        if (n < H)           v = ctxW[(size_t)k * H + n];
        else if (n < H + HA) v = attW1[(size_t)k * HA + (n - H)];
    }
    Wca[(size_t)n * 256 + k] = f2bf(v);
}

extern "C" void kernel_launch(void* const* d_in, const int* in_sizes, int n_in,
                              void* d_out, int out_size, void* d_ws, size_t ws_size,
                              hipStream_t stream)
{
    const float* x      = (const float*)d_in[0];
    const float* state  = (const float*)d_in[1];
    const float* enc_W  = (const float*)d_in[2];
    const float* enc_b  = (const float*)d_in[3];
    const float* enc_g  = (const float*)d_in[4];
    const float* enc_bt = (const float*)d_in[5];
    const float* core_W = (const float*)d_in[6];
    const float* core_b = (const float*)d_in[7];
    const float* core_g = (const float*)d_in[8];
    const float* core_bt= (const float*)d_in[9];
    const float* ctx_W  = (const float*)d_in[10];
    const float* ctx_b  = (const float*)d_in[11];
    const float* ctx_g  = (const float*)d_in[12];
    const float* ctx_bt = (const float*)d_in[13];
    const float* att_W1 = (const float*)d_in[14];
    const float* att_b1 = (const float*)d_in[15];
    const float* att_g  = (const float*)d_in[16];
    const float* att_bt = (const float*)d_in[17];
    const float* att_W2 = (const float*)d_in[18];
    const float* att_b2 = (const float*)d_in[19];
    const float* out_W  = (const float*)d_in[20];
    const float* out_b  = (const float*)d_in[21];
    float* out = (float*)d_out;

    float* PQ       = (float*)d_ws;                        // 16384*512 f32
    ushort_t* Abuf  = (ushort_t*)(PQ + (size_t)ROWS * PQS);// 16384*1088 bf16
    ushort_t* Wt    = Abuf + (size_t)ROWS * KP;            // 256*1088
    ushort_t* Wpq   = Wt + (size_t)256 * KP;               // 512*256
    ushort_t* Wca   = Wpq + (size_t)512 * 256;             // 384*256

    k_prepw  <<<256, 256, 0, stream>>>(out_W, Wt);
    k_prep_wpq<<<512, 256, 0, stream>>>(core_W, Wpq);
    k_prep_wca<<<384, 256, 0, stream>>>(ctx_W, att_W1, Wca);
    k_prepx  <<<ROWS, 256, 0, stream>>>(x, Abuf);
    k_enc    <<<ROWS / 32, 256, 0, stream>>>(state, enc_W, enc_b, enc_g, enc_bt, Abuf);
    // PQ = s1 @ [W_top | W_bot]  (bf16 MFMA)
    k_gemm   <<<(ROWS / 64) * 8, 256, 0, stream>>>(Abuf, KP, Wpq, 256, PQ, PQS,
                                                   nullptr, 8, 8, 512);
    k_ca     <<<ROWS / GCA, 512, 0, stream>>>(PQ, core_b, core_g, core_bt, Wca,
                                              ctx_b, ctx_g, ctx_bt,
                                              att_b1, att_g, att_bt, att_W2, att_b2,
                                              Abuf);
    // out = [s1 | eff | x] @ out_W + b  (bf16 MFMA)
    k_gemm   <<<(ROWS / 64) * 4, 256, 0, stream>>>(Abuf, KP, Wt, KP, out, H,
                                                   out_b, KP / 32, 4, H);
}